// Round 10
// baseline (176.376 us; speedup 1.0000x reference)
//
#include <hip/hip_runtime.h>
#include <hip/hip_fp16.h>

#define BATCH 8
#define S_LOG 9
#define SBUCKET 512          // nodes per bucket
#define KC 256               // max buckets (N <= 131071)
#define CB 1024              // blocks for count/scatter
#define TTILE 4096           // edges per sort tile (>= chunk => single tile)
#define EPT 8                // edges per thread per tile (contiguous)
#define RPT 30               // accum records per thread per chunk (registers)
#define SCAP (RPT * 512)     // 15360 records per accum sort chunk (120 KB LDS)

static inline size_t alignup(size_t x) { return (x + 255) & ~(size_t)255; }

__device__ __forceinline__ unsigned bf16hi(unsigned u) {
    // fp32 -> bf16 (rne), returned in LOW 16 bits
    return (u + 0x7FFFu + ((u >> 16) & 1u)) >> 16;
}

__device__ __forceinline__ int aligned_chunk(int E) {
    return (((E + CB - 1) / CB) + 15) & ~15;    // 16-elem aligned => 64B
}

// ---------------- pipeline kernels ----------------

// fused: blocks [0,CB) bucket-count (int4 loads, uint LDS atomics); blocks [CB,...)
// transpose y -> yT[node] = 8 bf16 (uint4)
__global__ __launch_bounds__(256)
void count_transpose_kernel(const int* __restrict__ ei0, unsigned* __restrict__ counts,
                            const float* __restrict__ y, uint4* __restrict__ yT,
                            int E, int N, int Npad) {
    __shared__ unsigned cnt[KC];
    int tid = threadIdx.x;
    if (blockIdx.x >= CB) {
        int n = (blockIdx.x - CB) * 256 + tid;
        if (n < Npad) {
            uint4 o = make_uint4(0u, 0u, 0u, 0u);
            if (n < N) {
                unsigned p[8];
#pragma unroll
                for (int b = 0; b < BATCH; ++b)
                    p[b] = bf16hi(__float_as_uint(y[(size_t)b * N + n]));
                o = make_uint4(p[0] | (p[1] << 16), p[2] | (p[3] << 16),
                               p[4] | (p[5] << 16), p[6] | (p[7] << 16));
            }
            yT[n] = o;
        }
        return;
    }
    cnt[tid] = 0;
    __syncthreads();
    int chunk = aligned_chunk(E);
    int lo = blockIdx.x * chunk;
    int hi = min(lo + chunk, E);
    for (int bi = lo; bi < hi; bi += 1024) {
        int idx = bi + tid * 4;
        if (idx + 4 <= hi) {
            int4 v = *(const int4*)(ei0 + idx);
            atomicAdd(&cnt[(unsigned)v.x >> S_LOG], 1u);
            atomicAdd(&cnt[(unsigned)v.y >> S_LOG], 1u);
            atomicAdd(&cnt[(unsigned)v.z >> S_LOG], 1u);
            atomicAdd(&cnt[(unsigned)v.w >> S_LOG], 1u);
        } else {
#pragma unroll
            for (int j = 0; j < 4; ++j) {
                int i2 = idx + j;
                if (i2 < hi) atomicAdd(&cnt[(unsigned)ei0[i2] >> S_LOG], 1u);
            }
        }
    }
    __syncthreads();
    counts[(size_t)tid * CB + blockIdx.x] = cnt[tid];   // [bucket][block]
}

// scanB1: one block per bucket — local exclusive prefix of counts[k][0..CB) -> base,
// and bucket total -> tot[k].
__global__ __launch_bounds__(256)
void scanB1_kernel(const unsigned* __restrict__ counts, unsigned* __restrict__ base,
                   unsigned* __restrict__ tot) {
    __shared__ unsigned ssum[256];
    int k = blockIdx.x, tid = threadIdx.x;
    const uint4* row4 = (const uint4*)(counts + (size_t)k * CB);
    uint4 v = row4[tid];
    unsigned lsum = v.x + v.y + v.z + v.w;
    ssum[tid] = lsum;
    __syncthreads();
    for (int off = 1; off < 256; off <<= 1) {
        unsigned u = ssum[tid];
        unsigned a = (tid >= off) ? ssum[tid - off] : 0u;
        __syncthreads();
        ssum[tid] = u + a;
        __syncthreads();
    }
    unsigned ex = ssum[tid] - lsum;
    if (tid == 255) tot[k] = ssum[255];
    uint4 o;
    o.x = ex;
    o.y = ex + v.x;
    o.z = o.y + v.y;
    o.w = o.z + v.z;
    ((uint4*)(base + (size_t)k * CB))[tid] = o;
}

// scanC: one block — exclusive scan of bucket totals -> bb[0..KC], bb[KC]=E
__global__ void scanC_kernel(const unsigned* __restrict__ tot,
                             unsigned* __restrict__ bb, int E, int K) {
    __shared__ unsigned sb[KC];
    int t = threadIdx.x;
    unsigned v = (t < K) ? tot[t] : 0u;
    sb[t] = v;
    __syncthreads();
    for (int off = 1; off < KC; off <<= 1) {
        unsigned u = sb[t];
        unsigned a = (t >= off) ? sb[t - off] : 0u;
        __syncthreads();
        sb[t] = u + a;
        __syncthreads();
    }
    bb[t] = sb[t] - v;
    if (t == KC - 1) bb[KC] = (unsigned)E;
}

// scatter: bucket-sort edges into w0coef records. 512 threads, single 4096-tile
// per block (chunk ~3136): one histogram + one scan + one stage + one drain —
// half the barriers of the 2048-tile version, and ~16-record (128B) bucket
// runs on the drain for full-line writes.
// record: .x = s1 | s0l<<17 ; .y = bf16(coef)<<16 | bf16(gea)
__global__ __launch_bounds__(512, 8)
void scatter_kernel(const int* __restrict__ ei0, const int* __restrict__ ei1,
                    const float* __restrict__ dw, const float* __restrict__ gea,
                    const unsigned* __restrict__ base, const unsigned* __restrict__ bb,
                    uint2* __restrict__ w0coef, int E) {
    __shared__ unsigned cursor[KC];
    __shared__ unsigned h[KC];
    __shared__ unsigned tstart[KC];
    __shared__ unsigned wsum[4];
    __shared__ uint2 srec[TTILE];            // 32 KB
    __shared__ unsigned char skey[TTILE];    // 4 KB
    int tid = threadIdx.x;
    if (tid < KC) cursor[tid] = base[(size_t)tid * CB + blockIdx.x] + bb[tid];
    int chunk = aligned_chunk(E);
    int lo = blockIdx.x * chunk;
    int hi = min(lo + chunk, E);
    __syncthreads();

    for (int tileLo = lo; tileLo < hi; tileLo += TTILE) {
        int tn = min(TTILE, hi - tileLo);
        if (tid < KC) h[tid] = 0;
        __syncthreads();

        int base_off = tid * EPT;
        unsigned k_r[EPT], w0_r[EPT], pk_r[EPT], rk_r[EPT];
        int s0a[EPT], s1a[EPT];
        float dwa[EPT], gea_a[EPT];
        bool anyv = base_off < tn;
        if (base_off + EPT <= tn) {
            // vector loads (tileLo 16-aligned, base_off multiple of 8)
            const int4* p0 = (const int4*)(ei0 + tileLo + base_off);
            const int4* p1 = (const int4*)(ei1 + tileLo + base_off);
            const float4* pd = (const float4*)(dw + tileLo + base_off);
            const float4* pg = (const float4*)(gea + tileLo + base_off);
            int4 a0 = p0[0], a1 = p0[1];
            int4 b0 = p1[0], b1 = p1[1];
            float4 d0 = pd[0], d1 = pd[1];
            float4 g0 = pg[0], g1 = pg[1];
            s0a[0]=a0.x; s0a[1]=a0.y; s0a[2]=a0.z; s0a[3]=a0.w;
            s0a[4]=a1.x; s0a[5]=a1.y; s0a[6]=a1.z; s0a[7]=a1.w;
            s1a[0]=b0.x; s1a[1]=b0.y; s1a[2]=b0.z; s1a[3]=b0.w;
            s1a[4]=b1.x; s1a[5]=b1.y; s1a[6]=b1.z; s1a[7]=b1.w;
            dwa[0]=d0.x; dwa[1]=d0.y; dwa[2]=d0.z; dwa[3]=d0.w;
            dwa[4]=d1.x; dwa[5]=d1.y; dwa[6]=d1.z; dwa[7]=d1.w;
            gea_a[0]=g0.x; gea_a[1]=g0.y; gea_a[2]=g0.z; gea_a[3]=g0.w;
            gea_a[4]=g1.x; gea_a[5]=g1.y; gea_a[6]=g1.z; gea_a[7]=g1.w;
#pragma unroll
            for (int j = 0; j < EPT; ++j) k_r[j] = 0u;   // mark all valid below
#pragma unroll
            for (int j = 0; j < EPT; ++j) {
                unsigned k = (unsigned)s0a[j] >> S_LOG;
                unsigned s0l = (unsigned)(s0a[j] & (SBUCKET - 1));
                k_r[j] = k;
                w0_r[j] = (unsigned)s1a[j] | (s0l << 17);
                float sig = 1.0f / (1.0f + __expf(-dwa[j]));
                pk_r[j] = (bf16hi(__float_as_uint(sqrtf(sig))) << 16) |
                          bf16hi(__float_as_uint(gea_a[j]));
            }
#pragma unroll
            for (int j = 0; j < EPT; ++j)
                rk_r[j] = atomicAdd(&h[k_r[j]], 1u);
        } else {
#pragma unroll
            for (int j = 0; j < EPT; ++j) {
                int off = base_off + j;
                k_r[j] = 0xFFFFFFFFu;
                if (off < tn) {
                    int i = tileLo + off;
                    int s0v = ei0[i];
                    int s1v = ei1[i];
                    unsigned k = (unsigned)s0v >> S_LOG;
                    unsigned s0l = (unsigned)(s0v & (SBUCKET - 1));
                    k_r[j] = k;
                    w0_r[j] = (unsigned)s1v | (s0l << 17);
                    float sig = 1.0f / (1.0f + __expf(-dw[i]));
                    pk_r[j] = (bf16hi(__float_as_uint(sqrtf(sig))) << 16) |
                              bf16hi(__float_as_uint(gea[i]));
                }
            }
#pragma unroll
            for (int j = 0; j < EPT; ++j)
                if (k_r[j] != 0xFFFFFFFFu) rk_r[j] = atomicAdd(&h[k_r[j]], 1u);
        }
        bool fullv = base_off + EPT <= tn;
        __syncthreads();

        // exclusive scan of h[256] via wave shuffles (threads 0..255, 4 waves)
        if (tid < KC) {
            unsigned hv = h[tid];
            unsigned v = hv;
            unsigned lane = tid & 63;
            unsigned wv = tid >> 6;
#pragma unroll
            for (int off = 1; off < 64; off <<= 1) {
                unsigned t = __shfl_up(v, off, 64);
                if (lane >= off) v += t;
            }
            if (lane == 63) wsum[wv] = v;
            __syncthreads();
            unsigned addv = 0;
#pragma unroll
            for (unsigned w = 0; w < 4; ++w)
                if (w < wv) addv += wsum[w];
            tstart[tid] = v + addv - hv;
        } else {
            __syncthreads();
        }
        __syncthreads();

        if (fullv) {
#pragma unroll
            for (int j = 0; j < EPT; ++j) {
                unsigned slot = tstart[k_r[j]] + rk_r[j];
                srec[slot] = make_uint2(w0_r[j], pk_r[j]);
                skey[slot] = (unsigned char)k_r[j];
            }
        } else if (anyv) {
#pragma unroll
            for (int j = 0; j < EPT; ++j)
                if (k_r[j] != 0xFFFFFFFFu) {
                    unsigned slot = tstart[k_r[j]] + rk_r[j];
                    srec[slot] = make_uint2(w0_r[j], pk_r[j]);
                    skey[slot] = (unsigned char)k_r[j];
                }
        }
        __syncthreads();

        for (int i = tid; i < tn; i += 512) {
            uint2 u = srec[i];
            unsigned k = skey[i];
            unsigned pos = cursor[k] + ((unsigned)i - tstart[k]);
            w0coef[pos] = u;
        }
        __syncthreads();
        if (tid < KC) cursor[tid] += h[tid];
        __syncthreads();
    }
}

// accum (owner-computes): one block per bucket, 512 threads, 1 node/thread.
// Per chunk (<=SCAP records): load the chunk ONCE into registers (rec[RPT],
// static indices), count s0l via LDS atomics, 8-wave scan, scatter from
// registers into node-sorted LDS — no second global read of w0coef (R9).
// Then each thread walks its node's contiguous run accumulating in fp32
// registers. Writes final out = 1 - acc/deg^2 directly.
__global__ __launch_bounds__(512)
void accum_kernel(const uint2* __restrict__ w0coef, const unsigned* __restrict__ bb,
                  const uint4* __restrict__ yT,
                  float* __restrict__ out, int N) {
    __shared__ uint2 srt[SCAP];              // 120 KB sorted records
    __shared__ unsigned bcnt[SBUCKET];       // 2 KB per-node count (chunk)
    __shared__ unsigned bcur[SBUCKET];       // 2 KB scatter cursors
    __shared__ unsigned wsums[8];
    int k = blockIdx.x, tid = threadIdx.x;
    int n0 = k << S_LOG;
    unsigned lane = tid & 63;
    unsigned wvi = tid >> 6;

    unsigned lo = bb[k], hi = bb[k + 1];

    // my node's y0, unpacked once
    uint4 y0r = yT[n0 + tid];
    float y0f[8];
    {
        unsigned yw[4] = {y0r.x, y0r.y, y0r.z, y0r.w};
#pragma unroll
        for (int p = 0; p < 4; ++p) {
            y0f[2 * p]     = __uint_as_float(yw[p] << 16);
            y0f[2 * p + 1] = __uint_as_float(yw[p] & 0xFFFF0000u);
        }
    }
    float acc[8] = {0.f, 0.f, 0.f, 0.f, 0.f, 0.f, 0.f, 0.f};
    float dega = 0.f;

    for (unsigned cbase = lo; cbase < hi; cbase += SCAP) {
        unsigned cn = min((unsigned)SCAP, hi - cbase);
        bcnt[tid] = 0u;
        __syncthreads();
        // single coalesced global read of the chunk into registers
        uint2 rec[RPT];
#pragma unroll
        for (int j = 0; j < RPT; ++j) {
            unsigned o = (unsigned)tid + (unsigned)j * 512u;
            rec[j] = (o < cn) ? w0coef[cbase + o] : make_uint2(0u, 0u);
        }
        // pass1: count s0l from registers (cheap uint LDS atomics)
#pragma unroll
        for (int j = 0; j < RPT; ++j) {
            unsigned o = (unsigned)tid + (unsigned)j * 512u;
            if (o < cn) atomicAdd(&bcnt[rec[j].x >> 17], 1u);
        }
        __syncthreads();
        // exclusive scan of bcnt[512] across 8 waves
        unsigned myc = bcnt[tid];
        unsigned v = myc;
#pragma unroll
        for (int off = 1; off < 64; off <<= 1) {
            unsigned t = __shfl_up(v, off, 64);
            if (lane >= off) v += t;
        }
        if (lane == 63) wsums[wvi] = v;
        __syncthreads();
        unsigned add = 0;
#pragma unroll
        for (unsigned w = 0; w < 8; ++w)
            if (w < wvi) add += wsums[w];
        unsigned myoff = v + add - myc;
        bcur[tid] = myoff;
        __syncthreads();
        // pass2: scatter from registers into srt sorted by node
#pragma unroll
        for (int j = 0; j < RPT; ++j) {
            unsigned o = (unsigned)tid + (unsigned)j * 512u;
            if (o < cn) {
                unsigned slot = atomicAdd(&bcur[rec[j].x >> 17], 1u);
                srt[slot] = rec[j];
            }
        }
        __syncthreads();
        // owner phase: walk my run with a 2-deep prefetch pipeline
        unsigned s = myoff, e = myoff + myc;
        uint2 r0 = make_uint2(0u, 0u), r1 = make_uint2(0u, 0u);
        uint4 g0 = make_uint4(0u, 0u, 0u, 0u), g1 = g0;
        if (s < e)     { r0 = srt[s];     g0 = yT[r0.x & 0x1FFFFu]; }
        if (s + 1 < e) { r1 = srt[s + 1]; g1 = yT[r1.x & 0x1FFFFu]; }
        for (unsigned i = s; i < e; ++i) {
            uint2 rc = r0; uint4 gc = g0;
            r0 = r1; g0 = g1;
            if (i + 2 < e) { r1 = srt[i + 2]; g1 = yT[r1.x & 0x1FFFFu]; }
            float cf = __uint_as_float(rc.y & 0xFFFF0000u);
            float ge = __uint_as_float(rc.y << 16);
            unsigned gw[4] = {gc.x, gc.y, gc.z, gc.w};
#pragma unroll
            for (int p = 0; p < 4; ++p) {
                float ga = __uint_as_float(gw[p] << 16);
                float gb = __uint_as_float(gw[p] & 0xFFFF0000u);
                acc[2 * p]     += cf * fmaxf(y0f[2 * p]     - ga, 0.0f);
                acc[2 * p + 1] += cf * fmaxf(y0f[2 * p + 1] - gb, 0.0f);
            }
            dega += ge;
        }
        __syncthreads();   // all owners done before LDS reuse next chunk
    }

    // final write: out[b*N + n] = 1 - acc[b]/deg^2 (coalesced per batch)
    int n = n0 + tid;
    if (n < N) {
        float invd = (dega != 0.0f) ? 1.0f / (dega * dega) : 0.0f;
#pragma unroll
        for (int b = 0; b < BATCH; ++b)
            out[(size_t)b * N + n] = 1.0f - acc[b] * invd;
    }
}

// ---------------- fallback (R1 path) ----------------

__global__ void fill_one_kernel(float* __restrict__ out, int n) {
    int i = blockIdx.x * blockDim.x + threadIdx.x;
    if (i < n) out[i] = 1.0f;
}

__global__ void zero_kernel(float* __restrict__ p, int n) {
    int i = blockIdx.x * blockDim.x + threadIdx.x;
    if (i < n) p[i] = 0.0f;
}

__global__ void deg_kernel(const float* __restrict__ gea,
                           const int* __restrict__ ei0,
                           float* __restrict__ deg, int E) {
    int e = blockIdx.x * blockDim.x + threadIdx.x;
    if (e < E) atomicAdd(&deg[ei0[e]], gea[e]);
}

__global__ void edge_kernel(const float* __restrict__ y,
                            const float* __restrict__ dw,
                            const int* __restrict__ ei0,
                            const int* __restrict__ ei1,
                            const float* __restrict__ deg,
                            float* __restrict__ out,
                            int E, int N) {
    int e = blockIdx.x * blockDim.x + threadIdx.x;
    if (e >= E) return;
    int s0 = ei0[e];
    int s1 = ei1[e];
    float d = deg[s0];
    float inv = 1.0f / (d * d);
    float sig = 1.0f / (1.0f + __expf(-dw[e]));
    float coef = sqrtf(sig) * inv;
#pragma unroll
    for (int b = 0; b < BATCH; ++b) {
        float y0 = y[(size_t)b * N + s0];
        float y1 = y[(size_t)b * N + s1];
        float gm = coef * fmaxf(y0 - y1, 0.0f);
        if (gm != 0.0f) atomicAdd(&out[(size_t)b * N + s0], -gm);
    }
}

// ---------------- launch ----------------

extern "C" void kernel_launch(void* const* d_in, const int* in_sizes, int n_in,
                              void* d_out, int out_size, void* d_ws, size_t ws_size,
                              hipStream_t stream) {
    const float* y   = (const float*)d_in[0];   // [B,N]
    const float* gea = (const float*)d_in[2];   // [E]
    const float* dw  = (const float*)d_in[3];   // [E]
    const int*   ei  = (const int*)d_in[4];     // [2,E]

    const int E = in_sizes[2];
    const int N = in_sizes[0] / BATCH;
    const int* ei0 = ei;
    const int* ei1 = ei + E;

    const int K = (N + SBUCKET - 1) >> S_LOG;
    const int Npad = K << S_LOG;

    size_t o_yT     = 0;
    size_t o_rcf    = o_yT     + alignup((size_t)Npad * 16);
    size_t o_counts = o_rcf    + alignup((size_t)E * 8);
    size_t o_base   = o_counts + alignup((size_t)KC * CB * 4);
    size_t o_tot    = o_base   + alignup((size_t)KC * CB * 4);
    size_t o_bb     = o_tot    + alignup((size_t)KC * 4);
    size_t need     = o_bb     + alignup((size_t)(KC + 1) * 4);

    if (K <= KC && N <= 131071 && ws_size >= need) {
        char* w = (char*)d_ws;
        uint4*    yT     = (uint4*)(w + o_yT);
        uint2*    w0coef = (uint2*)(w + o_rcf);
        unsigned* counts = (unsigned*)(w + o_counts);
        unsigned* base   = (unsigned*)(w + o_base);
        unsigned* tot    = (unsigned*)(w + o_tot);
        unsigned* bb     = (unsigned*)(w + o_bb);

        int tb = (Npad + 255) / 256;
        count_transpose_kernel<<<CB + tb, 256, 0, stream>>>(ei0, counts, y, yT,
                                                            E, N, Npad);
        scanB1_kernel<<<K, 256, 0, stream>>>(counts, base, tot);
        scanC_kernel<<<1, KC, 0, stream>>>(tot, bb, E, K);
        scatter_kernel<<<CB, 512, 0, stream>>>(ei0, ei1, dw, gea, base, bb,
                                               w0coef, E);
        accum_kernel<<<K, 512, 0, stream>>>(w0coef, bb, yT, (float*)d_out, N);
    } else {
        float* deg = (float*)d_ws;
        zero_kernel<<<(N + 255) / 256, 256, 0, stream>>>(deg, N);
        fill_one_kernel<<<(out_size + 255) / 256, 256, 0, stream>>>((float*)d_out, out_size);
        deg_kernel<<<(E + 255) / 256, 256, 0, stream>>>(gea, ei0, deg, E);
        edge_kernel<<<(E + 255) / 256, 256, 0, stream>>>(y, dw, ei0, ei1, deg,
                                                         (float*)d_out, E, N);
    }
}

// Round 11
// 148.014 us; speedup vs baseline: 1.1916x; 1.1916x over previous
//
#include <hip/hip_runtime.h>
#include <hip/hip_fp16.h>

#define BATCH 8
#define S_LOG 9
#define SBUCKET 512          // nodes per bucket
#define KC 256               // max buckets (N <= 131071)
#define CB 1024              // blocks for count/scatter
#define TTILE 4096           // edges per sort tile (>= chunk => single tile)
#define EPT 8                // edges per thread per tile (contiguous)
#define RPT 30               // accum records per thread per chunk (registers)
#define SCAP (RPT * 512)     // 15360 records per accum sort chunk (120 KB LDS)

static inline size_t alignup(size_t x) { return (x + 255) & ~(size_t)255; }

__device__ __forceinline__ unsigned bf16hi(unsigned u) {
    // fp32 -> bf16 (rne), returned in LOW 16 bits
    return (u + 0x7FFFu + ((u >> 16) & 1u)) >> 16;
}

__device__ __forceinline__ int aligned_chunk(int E) {
    return (((E + CB - 1) / CB) + 15) & ~15;    // 16-elem aligned => 64B
}

// ---------------- pipeline kernels ----------------

// fused: blocks [0,CB) bucket-count (int4 loads, uint LDS atomics); blocks [CB,...)
// transpose y -> yT[node] = 8 bf16 (uint4)
__global__ __launch_bounds__(256)
void count_transpose_kernel(const int* __restrict__ ei0, unsigned* __restrict__ counts,
                            const float* __restrict__ y, uint4* __restrict__ yT,
                            int E, int N, int Npad) {
    __shared__ unsigned cnt[KC];
    int tid = threadIdx.x;
    if (blockIdx.x >= CB) {
        int n = (blockIdx.x - CB) * 256 + tid;
        if (n < Npad) {
            uint4 o = make_uint4(0u, 0u, 0u, 0u);
            if (n < N) {
                unsigned p[8];
#pragma unroll
                for (int b = 0; b < BATCH; ++b)
                    p[b] = bf16hi(__float_as_uint(y[(size_t)b * N + n]));
                o = make_uint4(p[0] | (p[1] << 16), p[2] | (p[3] << 16),
                               p[4] | (p[5] << 16), p[6] | (p[7] << 16));
            }
            yT[n] = o;
        }
        return;
    }
    cnt[tid] = 0;
    __syncthreads();
    int chunk = aligned_chunk(E);
    int lo = blockIdx.x * chunk;
    int hi = min(lo + chunk, E);
    for (int bi = lo; bi < hi; bi += 1024) {
        int idx = bi + tid * 4;
        if (idx + 4 <= hi) {
            int4 v = *(const int4*)(ei0 + idx);
            atomicAdd(&cnt[(unsigned)v.x >> S_LOG], 1u);
            atomicAdd(&cnt[(unsigned)v.y >> S_LOG], 1u);
            atomicAdd(&cnt[(unsigned)v.z >> S_LOG], 1u);
            atomicAdd(&cnt[(unsigned)v.w >> S_LOG], 1u);
        } else {
#pragma unroll
            for (int j = 0; j < 4; ++j) {
                int i2 = idx + j;
                if (i2 < hi) atomicAdd(&cnt[(unsigned)ei0[i2] >> S_LOG], 1u);
            }
        }
    }
    __syncthreads();
    counts[(size_t)tid * CB + blockIdx.x] = cnt[tid];   // [bucket][block]
}

// scanB1: one block per bucket — local exclusive prefix of counts[k][0..CB) -> base,
// and bucket total -> tot[k].
__global__ __launch_bounds__(256)
void scanB1_kernel(const unsigned* __restrict__ counts, unsigned* __restrict__ base,
                   unsigned* __restrict__ tot) {
    __shared__ unsigned ssum[256];
    int k = blockIdx.x, tid = threadIdx.x;
    const uint4* row4 = (const uint4*)(counts + (size_t)k * CB);
    uint4 v = row4[tid];
    unsigned lsum = v.x + v.y + v.z + v.w;
    ssum[tid] = lsum;
    __syncthreads();
    for (int off = 1; off < 256; off <<= 1) {
        unsigned u = ssum[tid];
        unsigned a = (tid >= off) ? ssum[tid - off] : 0u;
        __syncthreads();
        ssum[tid] = u + a;
        __syncthreads();
    }
    unsigned ex = ssum[tid] - lsum;
    if (tid == 255) tot[k] = ssum[255];
    uint4 o;
    o.x = ex;
    o.y = ex + v.x;
    o.z = o.y + v.y;
    o.w = o.z + v.z;
    ((uint4*)(base + (size_t)k * CB))[tid] = o;
}

// scanC: one block — exclusive scan of bucket totals -> bb[0..KC], bb[KC]=E
__global__ void scanC_kernel(const unsigned* __restrict__ tot,
                             unsigned* __restrict__ bb, int E, int K) {
    __shared__ unsigned sb[KC];
    int t = threadIdx.x;
    unsigned v = (t < K) ? tot[t] : 0u;
    sb[t] = v;
    __syncthreads();
    for (int off = 1; off < KC; off <<= 1) {
        unsigned u = sb[t];
        unsigned a = (t >= off) ? sb[t - off] : 0u;
        __syncthreads();
        sb[t] = u + a;
        __syncthreads();
    }
    bb[t] = sb[t] - v;
    if (t == KC - 1) bb[KC] = (unsigned)E;
}

// scatter: bucket-sort edges into w0coef records. 512 threads, single 4096-tile
// per block (chunk ~3136): one histogram + one scan + one stage + one drain.
// __launch_bounds__(512, 4) => 128-VGPR cap: no spill (R10's (512,8) forced a
// 64-VGPR cap -> scratch spill -> 134 MB write amplification).
// record: .x = s1 | s0l<<17 ; .y = bf16(coef)<<16 | bf16(gea)
__global__ __launch_bounds__(512, 4)
void scatter_kernel(const int* __restrict__ ei0, const int* __restrict__ ei1,
                    const float* __restrict__ dw, const float* __restrict__ gea,
                    const unsigned* __restrict__ base, const unsigned* __restrict__ bb,
                    uint2* __restrict__ w0coef, int E) {
    __shared__ unsigned cursor[KC];
    __shared__ unsigned h[KC];
    __shared__ unsigned tstart[KC];
    __shared__ unsigned wsum[4];
    __shared__ uint2 srec[TTILE];            // 32 KB
    __shared__ unsigned char skey[TTILE];    // 4 KB
    int tid = threadIdx.x;
    if (tid < KC) cursor[tid] = base[(size_t)tid * CB + blockIdx.x] + bb[tid];
    int chunk = aligned_chunk(E);
    int lo = blockIdx.x * chunk;
    int hi = min(lo + chunk, E);
    __syncthreads();

    for (int tileLo = lo; tileLo < hi; tileLo += TTILE) {
        int tn = min(TTILE, hi - tileLo);
        if (tid < KC) h[tid] = 0;
        __syncthreads();

        int base_off = tid * EPT;
        unsigned k_r[EPT], w0_r[EPT], pk_r[EPT], rk_r[EPT];
        int s0a[EPT], s1a[EPT];
        float dwa[EPT], gea_a[EPT];
        bool anyv = base_off < tn;
        if (base_off + EPT <= tn) {
            // vector loads (tileLo 16-aligned, base_off multiple of 8)
            const int4* p0 = (const int4*)(ei0 + tileLo + base_off);
            const int4* p1 = (const int4*)(ei1 + tileLo + base_off);
            const float4* pd = (const float4*)(dw + tileLo + base_off);
            const float4* pg = (const float4*)(gea + tileLo + base_off);
            int4 a0 = p0[0], a1 = p0[1];
            int4 b0 = p1[0], b1 = p1[1];
            float4 d0 = pd[0], d1 = pd[1];
            float4 g0 = pg[0], g1 = pg[1];
            s0a[0]=a0.x; s0a[1]=a0.y; s0a[2]=a0.z; s0a[3]=a0.w;
            s0a[4]=a1.x; s0a[5]=a1.y; s0a[6]=a1.z; s0a[7]=a1.w;
            s1a[0]=b0.x; s1a[1]=b0.y; s1a[2]=b0.z; s1a[3]=b0.w;
            s1a[4]=b1.x; s1a[5]=b1.y; s1a[6]=b1.z; s1a[7]=b1.w;
            dwa[0]=d0.x; dwa[1]=d0.y; dwa[2]=d0.z; dwa[3]=d0.w;
            dwa[4]=d1.x; dwa[5]=d1.y; dwa[6]=d1.z; dwa[7]=d1.w;
            gea_a[0]=g0.x; gea_a[1]=g0.y; gea_a[2]=g0.z; gea_a[3]=g0.w;
            gea_a[4]=g1.x; gea_a[5]=g1.y; gea_a[6]=g1.z; gea_a[7]=g1.w;
#pragma unroll
            for (int j = 0; j < EPT; ++j) k_r[j] = 0u;   // mark all valid below
#pragma unroll
            for (int j = 0; j < EPT; ++j) {
                unsigned k = (unsigned)s0a[j] >> S_LOG;
                unsigned s0l = (unsigned)(s0a[j] & (SBUCKET - 1));
                k_r[j] = k;
                w0_r[j] = (unsigned)s1a[j] | (s0l << 17);
                float sig = 1.0f / (1.0f + __expf(-dwa[j]));
                pk_r[j] = (bf16hi(__float_as_uint(sqrtf(sig))) << 16) |
                          bf16hi(__float_as_uint(gea_a[j]));
            }
#pragma unroll
            for (int j = 0; j < EPT; ++j)
                rk_r[j] = atomicAdd(&h[k_r[j]], 1u);
        } else {
#pragma unroll
            for (int j = 0; j < EPT; ++j) {
                int off = base_off + j;
                k_r[j] = 0xFFFFFFFFu;
                if (off < tn) {
                    int i = tileLo + off;
                    int s0v = ei0[i];
                    int s1v = ei1[i];
                    unsigned k = (unsigned)s0v >> S_LOG;
                    unsigned s0l = (unsigned)(s0v & (SBUCKET - 1));
                    k_r[j] = k;
                    w0_r[j] = (unsigned)s1v | (s0l << 17);
                    float sig = 1.0f / (1.0f + __expf(-dw[i]));
                    pk_r[j] = (bf16hi(__float_as_uint(sqrtf(sig))) << 16) |
                              bf16hi(__float_as_uint(gea[i]));
                }
            }
#pragma unroll
            for (int j = 0; j < EPT; ++j)
                if (k_r[j] != 0xFFFFFFFFu) rk_r[j] = atomicAdd(&h[k_r[j]], 1u);
        }
        bool fullv = base_off + EPT <= tn;
        __syncthreads();

        // exclusive scan of h[256]: all 8 waves run the shuffle scan (waves
        // 4..7 on zeros), barriers uniform — no divergent __syncthreads.
        unsigned lane = tid & 63;
        unsigned wv = tid >> 6;
        unsigned hv = (tid < KC) ? h[tid] : 0u;
        unsigned v = hv;
#pragma unroll
        for (int off = 1; off < 64; off <<= 1) {
            unsigned t = __shfl_up(v, off, 64);
            if (lane >= off) v += t;
        }
        if (lane == 63 && wv < 4) wsum[wv] = v;
        __syncthreads();
        unsigned addv = 0;
#pragma unroll
        for (unsigned w = 0; w < 4; ++w)
            if (w < wv) addv += wsum[w];
        if (tid < KC) tstart[tid] = v + addv - hv;
        __syncthreads();

        if (fullv) {
#pragma unroll
            for (int j = 0; j < EPT; ++j) {
                unsigned slot = tstart[k_r[j]] + rk_r[j];
                srec[slot] = make_uint2(w0_r[j], pk_r[j]);
                skey[slot] = (unsigned char)k_r[j];
            }
        } else if (anyv) {
#pragma unroll
            for (int j = 0; j < EPT; ++j)
                if (k_r[j] != 0xFFFFFFFFu) {
                    unsigned slot = tstart[k_r[j]] + rk_r[j];
                    srec[slot] = make_uint2(w0_r[j], pk_r[j]);
                    skey[slot] = (unsigned char)k_r[j];
                }
        }
        __syncthreads();

        for (int i = tid; i < tn; i += 512) {
            uint2 u = srec[i];
            unsigned k = skey[i];
            unsigned pos = cursor[k] + ((unsigned)i - tstart[k]);
            w0coef[pos] = u;
        }
        __syncthreads();
        if (tid < KC) cursor[tid] += h[tid];
        __syncthreads();
    }
}

// accum (owner-computes): one block per bucket, 512 threads, 1 node/thread.
// Per chunk (<=SCAP records): load the chunk ONCE into registers (rec[RPT],
// static indices), count s0l via LDS atomics, 8-wave scan, scatter from
// registers into node-sorted LDS — no second global read of w0coef (R9).
// Then each thread walks its node's contiguous run accumulating in fp32
// registers. Writes final out = 1 - acc/deg^2 directly.
__global__ __launch_bounds__(512)
void accum_kernel(const uint2* __restrict__ w0coef, const unsigned* __restrict__ bb,
                  const uint4* __restrict__ yT,
                  float* __restrict__ out, int N) {
    __shared__ uint2 srt[SCAP];              // 120 KB sorted records
    __shared__ unsigned bcnt[SBUCKET];       // 2 KB per-node count (chunk)
    __shared__ unsigned bcur[SBUCKET];       // 2 KB scatter cursors
    __shared__ unsigned wsums[8];
    int k = blockIdx.x, tid = threadIdx.x;
    int n0 = k << S_LOG;
    unsigned lane = tid & 63;
    unsigned wvi = tid >> 6;

    unsigned lo = bb[k], hi = bb[k + 1];

    // my node's y0, unpacked once
    uint4 y0r = yT[n0 + tid];
    float y0f[8];
    {
        unsigned yw[4] = {y0r.x, y0r.y, y0r.z, y0r.w};
#pragma unroll
        for (int p = 0; p < 4; ++p) {
            y0f[2 * p]     = __uint_as_float(yw[p] << 16);
            y0f[2 * p + 1] = __uint_as_float(yw[p] & 0xFFFF0000u);
        }
    }
    float acc[8] = {0.f, 0.f, 0.f, 0.f, 0.f, 0.f, 0.f, 0.f};
    float dega = 0.f;

    for (unsigned cbase = lo; cbase < hi; cbase += SCAP) {
        unsigned cn = min((unsigned)SCAP, hi - cbase);
        bcnt[tid] = 0u;
        __syncthreads();
        // single coalesced global read of the chunk into registers
        uint2 rec[RPT];
#pragma unroll
        for (int j = 0; j < RPT; ++j) {
            unsigned o = (unsigned)tid + (unsigned)j * 512u;
            rec[j] = (o < cn) ? w0coef[cbase + o] : make_uint2(0u, 0u);
        }
        // pass1: count s0l from registers (cheap uint LDS atomics)
#pragma unroll
        for (int j = 0; j < RPT; ++j) {
            unsigned o = (unsigned)tid + (unsigned)j * 512u;
            if (o < cn) atomicAdd(&bcnt[rec[j].x >> 17], 1u);
        }
        __syncthreads();
        // exclusive scan of bcnt[512] across 8 waves
        unsigned myc = bcnt[tid];
        unsigned v = myc;
#pragma unroll
        for (int off = 1; off < 64; off <<= 1) {
            unsigned t = __shfl_up(v, off, 64);
            if (lane >= off) v += t;
        }
        if (lane == 63) wsums[wvi] = v;
        __syncthreads();
        unsigned add = 0;
#pragma unroll
        for (unsigned w = 0; w < 8; ++w)
            if (w < wvi) add += wsums[w];
        unsigned myoff = v + add - myc;
        bcur[tid] = myoff;
        __syncthreads();
        // pass2: scatter from registers into srt sorted by node
#pragma unroll
        for (int j = 0; j < RPT; ++j) {
            unsigned o = (unsigned)tid + (unsigned)j * 512u;
            if (o < cn) {
                unsigned slot = atomicAdd(&bcur[rec[j].x >> 17], 1u);
                srt[slot] = rec[j];
            }
        }
        __syncthreads();
        // owner phase: walk my run with a 2-deep prefetch pipeline
        unsigned s = myoff, e = myoff + myc;
        uint2 r0 = make_uint2(0u, 0u), r1 = make_uint2(0u, 0u);
        uint4 g0 = make_uint4(0u, 0u, 0u, 0u), g1 = g0;
        if (s < e)     { r0 = srt[s];     g0 = yT[r0.x & 0x1FFFFu]; }
        if (s + 1 < e) { r1 = srt[s + 1]; g1 = yT[r1.x & 0x1FFFFu]; }
        for (unsigned i = s; i < e; ++i) {
            uint2 rc = r0; uint4 gc = g0;
            r0 = r1; g0 = g1;
            if (i + 2 < e) { r1 = srt[i + 2]; g1 = yT[r1.x & 0x1FFFFu]; }
            float cf = __uint_as_float(rc.y & 0xFFFF0000u);
            float ge = __uint_as_float(rc.y << 16);
            unsigned gw[4] = {gc.x, gc.y, gc.z, gc.w};
#pragma unroll
            for (int p = 0; p < 4; ++p) {
                float ga = __uint_as_float(gw[p] << 16);
                float gb = __uint_as_float(gw[p] & 0xFFFF0000u);
                acc[2 * p]     += cf * fmaxf(y0f[2 * p]     - ga, 0.0f);
                acc[2 * p + 1] += cf * fmaxf(y0f[2 * p + 1] - gb, 0.0f);
            }
            dega += ge;
        }
        __syncthreads();   // all owners done before LDS reuse next chunk
    }

    // final write: out[b*N + n] = 1 - acc[b]/deg^2 (coalesced per batch)
    int n = n0 + tid;
    if (n < N) {
        float invd = (dega != 0.0f) ? 1.0f / (dega * dega) : 0.0f;
#pragma unroll
        for (int b = 0; b < BATCH; ++b)
            out[(size_t)b * N + n] = 1.0f - acc[b] * invd;
    }
}

// ---------------- fallback (R1 path) ----------------

__global__ void fill_one_kernel(float* __restrict__ out, int n) {
    int i = blockIdx.x * blockDim.x + threadIdx.x;
    if (i < n) out[i] = 1.0f;
}

__global__ void zero_kernel(float* __restrict__ p, int n) {
    int i = blockIdx.x * blockDim.x + threadIdx.x;
    if (i < n) p[i] = 0.0f;
}

__global__ void deg_kernel(const float* __restrict__ gea,
                           const int* __restrict__ ei0,
                           float* __restrict__ deg, int E) {
    int e = blockIdx.x * blockDim.x + threadIdx.x;
    if (e < E) atomicAdd(&deg[ei0[e]], gea[e]);
}

__global__ void edge_kernel(const float* __restrict__ y,
                            const float* __restrict__ dw,
                            const int* __restrict__ ei0,
                            const int* __restrict__ ei1,
                            const float* __restrict__ deg,
                            float* __restrict__ out,
                            int E, int N) {
    int e = blockIdx.x * blockDim.x + threadIdx.x;
    if (e >= E) return;
    int s0 = ei0[e];
    int s1 = ei1[e];
    float d = deg[s0];
    float inv = 1.0f / (d * d);
    float sig = 1.0f / (1.0f + __expf(-dw[e]));
    float coef = sqrtf(sig) * inv;
#pragma unroll
    for (int b = 0; b < BATCH; ++b) {
        float y0 = y[(size_t)b * N + s0];
        float y1 = y[(size_t)b * N + s1];
        float gm = coef * fmaxf(y0 - y1, 0.0f);
        if (gm != 0.0f) atomicAdd(&out[(size_t)b * N + s0], -gm);
    }
}

// ---------------- launch ----------------

extern "C" void kernel_launch(void* const* d_in, const int* in_sizes, int n_in,
                              void* d_out, int out_size, void* d_ws, size_t ws_size,
                              hipStream_t stream) {
    const float* y   = (const float*)d_in[0];   // [B,N]
    const float* gea = (const float*)d_in[2];   // [E]
    const float* dw  = (const float*)d_in[3];   // [E]
    const int*   ei  = (const int*)d_in[4];     // [2,E]

    const int E = in_sizes[2];
    const int N = in_sizes[0] / BATCH;
    const int* ei0 = ei;
    const int* ei1 = ei + E;

    const int K = (N + SBUCKET - 1) >> S_LOG;
    const int Npad = K << S_LOG;

    size_t o_yT     = 0;
    size_t o_rcf    = o_yT     + alignup((size_t)Npad * 16);
    size_t o_counts = o_rcf    + alignup((size_t)E * 8);
    size_t o_base   = o_counts + alignup((size_t)KC * CB * 4);
    size_t o_tot    = o_base   + alignup((size_t)KC * CB * 4);
    size_t o_bb     = o_tot    + alignup((size_t)KC * 4);
    size_t need     = o_bb     + alignup((size_t)(KC + 1) * 4);

    if (K <= KC && N <= 131071 && ws_size >= need) {
        char* w = (char*)d_ws;
        uint4*    yT     = (uint4*)(w + o_yT);
        uint2*    w0coef = (uint2*)(w + o_rcf);
        unsigned* counts = (unsigned*)(w + o_counts);
        unsigned* base   = (unsigned*)(w + o_base);
        unsigned* tot    = (unsigned*)(w + o_tot);
        unsigned* bb     = (unsigned*)(w + o_bb);

        int tb = (Npad + 255) / 256;
        count_transpose_kernel<<<CB + tb, 256, 0, stream>>>(ei0, counts, y, yT,
                                                            E, N, Npad);
        scanB1_kernel<<<K, 256, 0, stream>>>(counts, base, tot);
        scanC_kernel<<<1, KC, 0, stream>>>(tot, bb, E, K);
        scatter_kernel<<<CB, 512, 0, stream>>>(ei0, ei1, dw, gea, base, bb,
                                               w0coef, E);
        accum_kernel<<<K, 512, 0, stream>>>(w0coef, bb, yT, (float*)d_out, N);
    } else {
        float* deg = (float*)d_ws;
        zero_kernel<<<(N + 255) / 256, 256, 0, stream>>>(deg, N);
        fill_one_kernel<<<(out_size + 255) / 256, 256, 0, stream>>>((float*)d_out, out_size);
        deg_kernel<<<(E + 255) / 256, 256, 0, stream>>>(gea, ei0, deg, E);
        edge_kernel<<<(E + 255) / 256, 256, 0, stream>>>(y, dw, ei0, ei1, deg,
                                                         (float*)d_out, E, N);
    }
}

// Round 12
// 144.436 us; speedup vs baseline: 1.2211x; 1.0248x over previous
//
#include <hip/hip_runtime.h>
#include <hip/hip_fp16.h>

#define BATCH 8
#define S_LOG 9
#define SBUCKET 512          // nodes per bucket
#define KC 256               // max buckets (N <= 131071)
#define CB 1024              // blocks for count/scatter
#define TTILE 4096           // edges per sort tile (>= chunk => single tile)
#define EPT 8                // edges per thread per tile (contiguous)
#define RPT 34               // accum records per thread per chunk (registers)
#define SCAP (RPT * 512)     // 17408 records per accum sort chunk (136 KB LDS)

static inline size_t alignup(size_t x) { return (x + 255) & ~(size_t)255; }

__device__ __forceinline__ unsigned bf16hi(unsigned u) {
    // fp32 -> bf16 (rne), returned in LOW 16 bits
    return (u + 0x7FFFu + ((u >> 16) & 1u)) >> 16;
}

__device__ __forceinline__ int aligned_chunk(int E) {
    return (((E + CB - 1) / CB) + 15) & ~15;    // 16-elem aligned => 64B
}

// ---------------- pipeline kernels ----------------

// fused: blocks [0,CB) bucket-count (int4 loads, uint LDS atomics); blocks [CB,...)
// transpose y -> yT[node] = 8 bf16 (uint4)
__global__ __launch_bounds__(256)
void count_transpose_kernel(const int* __restrict__ ei0, unsigned* __restrict__ counts,
                            const float* __restrict__ y, uint4* __restrict__ yT,
                            int E, int N, int Npad) {
    __shared__ unsigned cnt[KC];
    int tid = threadIdx.x;
    if (blockIdx.x >= CB) {
        int n = (blockIdx.x - CB) * 256 + tid;
        if (n < Npad) {
            uint4 o = make_uint4(0u, 0u, 0u, 0u);
            if (n < N) {
                unsigned p[8];
#pragma unroll
                for (int b = 0; b < BATCH; ++b)
                    p[b] = bf16hi(__float_as_uint(y[(size_t)b * N + n]));
                o = make_uint4(p[0] | (p[1] << 16), p[2] | (p[3] << 16),
                               p[4] | (p[5] << 16), p[6] | (p[7] << 16));
            }
            yT[n] = o;
        }
        return;
    }
    cnt[tid] = 0;
    __syncthreads();
    int chunk = aligned_chunk(E);
    int lo = blockIdx.x * chunk;
    int hi = min(lo + chunk, E);
    for (int bi = lo; bi < hi; bi += 1024) {
        int idx = bi + tid * 4;
        if (idx + 4 <= hi) {
            int4 v = *(const int4*)(ei0 + idx);
            atomicAdd(&cnt[(unsigned)v.x >> S_LOG], 1u);
            atomicAdd(&cnt[(unsigned)v.y >> S_LOG], 1u);
            atomicAdd(&cnt[(unsigned)v.z >> S_LOG], 1u);
            atomicAdd(&cnt[(unsigned)v.w >> S_LOG], 1u);
        } else {
#pragma unroll
            for (int j = 0; j < 4; ++j) {
                int i2 = idx + j;
                if (i2 < hi) atomicAdd(&cnt[(unsigned)ei0[i2] >> S_LOG], 1u);
            }
        }
    }
    __syncthreads();
    counts[(size_t)tid * CB + blockIdx.x] = cnt[tid];   // [bucket][block]
}

// scanB1: one block per bucket — local exclusive prefix of counts[k][0..CB) -> base,
// and bucket total -> tot[k].
__global__ __launch_bounds__(256)
void scanB1_kernel(const unsigned* __restrict__ counts, unsigned* __restrict__ base,
                   unsigned* __restrict__ tot) {
    __shared__ unsigned ssum[256];
    int k = blockIdx.x, tid = threadIdx.x;
    const uint4* row4 = (const uint4*)(counts + (size_t)k * CB);
    uint4 v = row4[tid];
    unsigned lsum = v.x + v.y + v.z + v.w;
    ssum[tid] = lsum;
    __syncthreads();
    for (int off = 1; off < 256; off <<= 1) {
        unsigned u = ssum[tid];
        unsigned a = (tid >= off) ? ssum[tid - off] : 0u;
        __syncthreads();
        ssum[tid] = u + a;
        __syncthreads();
    }
    unsigned ex = ssum[tid] - lsum;
    if (tid == 255) tot[k] = ssum[255];
    uint4 o;
    o.x = ex;
    o.y = ex + v.x;
    o.z = o.y + v.y;
    o.w = o.z + v.z;
    ((uint4*)(base + (size_t)k * CB))[tid] = o;
}

// scatter: bucket-sort edges into w0coef records. 512 threads, single 4096-tile
// per block (chunk ~3136). Preamble computes the global bucket bases bb[] from
// tot[] in-block (256-elem shuffle scan) — scanC dispatch eliminated (R12).
// record: .x = s1 | s0l<<17 ; .y = bf16(coef)<<16 | bf16(gea)
__global__ __launch_bounds__(512, 4)
void scatter_kernel(const int* __restrict__ ei0, const int* __restrict__ ei1,
                    const float* __restrict__ dw, const float* __restrict__ gea,
                    const unsigned* __restrict__ base, const unsigned* __restrict__ tot,
                    uint2* __restrict__ w0coef, int E, int K) {
    __shared__ unsigned cursor[KC];
    __shared__ unsigned h[KC];
    __shared__ unsigned tstart[KC];
    __shared__ unsigned wsum[4];
    __shared__ uint2 srec[TTILE];            // 32 KB
    __shared__ unsigned char skey[TTILE];    // 4 KB
    int tid = threadIdx.x;
    unsigned lane = tid & 63;
    unsigned wv = tid >> 6;

    // preamble: bb[tid] = exclusive scan of tot (tid<K), fold into cursor init
    {
        unsigned tv = (tid < KC && tid < K) ? tot[tid] : 0u;
        unsigned v = tv;
#pragma unroll
        for (int off = 1; off < 64; off <<= 1) {
            unsigned t = __shfl_up(v, off, 64);
            if (lane >= off) v += t;
        }
        if (lane == 63 && wv < 4) wsum[wv] = v;
        __syncthreads();
        unsigned addv = 0;
#pragma unroll
        for (unsigned w = 0; w < 4; ++w)
            if (w < wv) addv += wsum[w];
        if (tid < KC)
            cursor[tid] = base[(size_t)tid * CB + blockIdx.x] + (v + addv - tv);
        __syncthreads();
    }

    int chunk = aligned_chunk(E);
    int lo = blockIdx.x * chunk;
    int hi = min(lo + chunk, E);

    for (int tileLo = lo; tileLo < hi; tileLo += TTILE) {
        int tn = min(TTILE, hi - tileLo);
        if (tid < KC) h[tid] = 0;
        __syncthreads();

        int base_off = tid * EPT;
        unsigned k_r[EPT], w0_r[EPT], pk_r[EPT], rk_r[EPT];
        int s0a[EPT], s1a[EPT];
        float dwa[EPT], gea_a[EPT];
        bool anyv = base_off < tn;
        if (base_off + EPT <= tn) {
            // vector loads (tileLo 16-aligned, base_off multiple of 8)
            const int4* p0 = (const int4*)(ei0 + tileLo + base_off);
            const int4* p1 = (const int4*)(ei1 + tileLo + base_off);
            const float4* pd = (const float4*)(dw + tileLo + base_off);
            const float4* pg = (const float4*)(gea + tileLo + base_off);
            int4 a0 = p0[0], a1 = p0[1];
            int4 b0 = p1[0], b1 = p1[1];
            float4 d0 = pd[0], d1 = pd[1];
            float4 g0 = pg[0], g1 = pg[1];
            s0a[0]=a0.x; s0a[1]=a0.y; s0a[2]=a0.z; s0a[3]=a0.w;
            s0a[4]=a1.x; s0a[5]=a1.y; s0a[6]=a1.z; s0a[7]=a1.w;
            s1a[0]=b0.x; s1a[1]=b0.y; s1a[2]=b0.z; s1a[3]=b0.w;
            s1a[4]=b1.x; s1a[5]=b1.y; s1a[6]=b1.z; s1a[7]=b1.w;
            dwa[0]=d0.x; dwa[1]=d0.y; dwa[2]=d0.z; dwa[3]=d0.w;
            dwa[4]=d1.x; dwa[5]=d1.y; dwa[6]=d1.z; dwa[7]=d1.w;
            gea_a[0]=g0.x; gea_a[1]=g0.y; gea_a[2]=g0.z; gea_a[3]=g0.w;
            gea_a[4]=g1.x; gea_a[5]=g1.y; gea_a[6]=g1.z; gea_a[7]=g1.w;
#pragma unroll
            for (int j = 0; j < EPT; ++j) k_r[j] = 0u;   // mark all valid below
#pragma unroll
            for (int j = 0; j < EPT; ++j) {
                unsigned k = (unsigned)s0a[j] >> S_LOG;
                unsigned s0l = (unsigned)(s0a[j] & (SBUCKET - 1));
                k_r[j] = k;
                w0_r[j] = (unsigned)s1a[j] | (s0l << 17);
                float sig = 1.0f / (1.0f + __expf(-dwa[j]));
                pk_r[j] = (bf16hi(__float_as_uint(sqrtf(sig))) << 16) |
                          bf16hi(__float_as_uint(gea_a[j]));
            }
#pragma unroll
            for (int j = 0; j < EPT; ++j)
                rk_r[j] = atomicAdd(&h[k_r[j]], 1u);
        } else {
#pragma unroll
            for (int j = 0; j < EPT; ++j) {
                int off = base_off + j;
                k_r[j] = 0xFFFFFFFFu;
                if (off < tn) {
                    int i = tileLo + off;
                    int s0v = ei0[i];
                    int s1v = ei1[i];
                    unsigned k = (unsigned)s0v >> S_LOG;
                    unsigned s0l = (unsigned)(s0v & (SBUCKET - 1));
                    k_r[j] = k;
                    w0_r[j] = (unsigned)s1v | (s0l << 17);
                    float sig = 1.0f / (1.0f + __expf(-dw[i]));
                    pk_r[j] = (bf16hi(__float_as_uint(sqrtf(sig))) << 16) |
                              bf16hi(__float_as_uint(gea[i]));
                }
            }
#pragma unroll
            for (int j = 0; j < EPT; ++j)
                if (k_r[j] != 0xFFFFFFFFu) rk_r[j] = atomicAdd(&h[k_r[j]], 1u);
        }
        bool fullv = base_off + EPT <= tn;
        __syncthreads();

        // exclusive scan of h[256]: all 8 waves run the shuffle scan (waves
        // 4..7 on zeros), barriers uniform — no divergent __syncthreads.
        unsigned hv = (tid < KC) ? h[tid] : 0u;
        unsigned v = hv;
#pragma unroll
        for (int off = 1; off < 64; off <<= 1) {
            unsigned t = __shfl_up(v, off, 64);
            if (lane >= off) v += t;
        }
        if (lane == 63 && wv < 4) wsum[wv] = v;
        __syncthreads();
        unsigned addv = 0;
#pragma unroll
        for (unsigned w = 0; w < 4; ++w)
            if (w < wv) addv += wsum[w];
        if (tid < KC) tstart[tid] = v + addv - hv;
        __syncthreads();

        if (fullv) {
#pragma unroll
            for (int j = 0; j < EPT; ++j) {
                unsigned slot = tstart[k_r[j]] + rk_r[j];
                srec[slot] = make_uint2(w0_r[j], pk_r[j]);
                skey[slot] = (unsigned char)k_r[j];
            }
        } else if (anyv) {
#pragma unroll
            for (int j = 0; j < EPT; ++j)
                if (k_r[j] != 0xFFFFFFFFu) {
                    unsigned slot = tstart[k_r[j]] + rk_r[j];
                    srec[slot] = make_uint2(w0_r[j], pk_r[j]);
                    skey[slot] = (unsigned char)k_r[j];
                }
        }
        __syncthreads();

        for (int i = tid; i < tn; i += 512) {
            uint2 u = srec[i];
            unsigned k = skey[i];
            unsigned pos = cursor[k] + ((unsigned)i - tstart[k]);
            w0coef[pos] = u;
        }
        __syncthreads();
        if (tid < KC) cursor[tid] += h[tid];
        __syncthreads();
    }
}

// accum (owner-computes): one block per bucket, 512 threads, 1 node/thread.
// SCAP=17408 (>max bucket ~16.8K for this input) => single chunk per bucket;
// chunk loop kept for general safety. Preamble derives lo/hi from tot[] scan
// (scanC eliminated). Per chunk: load records ONCE into registers, count s0l
// via LDS atomics, 8-wave scan, scatter from registers into node-sorted LDS,
// then each thread walks its node's contiguous run in fp32 registers and
// writes final out = 1 - acc/deg^2 directly.
__global__ __launch_bounds__(512)
void accum_kernel(const uint2* __restrict__ w0coef, const unsigned* __restrict__ tot,
                  const uint4* __restrict__ yT,
                  float* __restrict__ out, int N, int K) {
    __shared__ uint2 srt[SCAP];              // 136 KB sorted records
    __shared__ unsigned bcnt[SBUCKET];       // 2 KB per-node count (chunk)
    __shared__ unsigned bcur[SBUCKET];       // 2 KB scatter cursors
    __shared__ unsigned binc[KC];            // 1 KB inclusive scan of tot
    __shared__ unsigned wsums[8];
    int k = blockIdx.x, tid = threadIdx.x;
    int n0 = k << S_LOG;
    unsigned lane = tid & 63;
    unsigned wvi = tid >> 6;

    // preamble: inclusive scan of tot -> binc; lo/hi for this bucket
    {
        unsigned tv = (tid < KC && tid < K) ? tot[tid] : 0u;
        unsigned v = tv;
#pragma unroll
        for (int off = 1; off < 64; off <<= 1) {
            unsigned t = __shfl_up(v, off, 64);
            if (lane >= off) v += t;
        }
        if (lane == 63 && wvi < 4) wsums[wvi] = v;
        __syncthreads();
        unsigned add = 0;
#pragma unroll
        for (unsigned w = 0; w < 4; ++w)
            if (w < wvi) add += wsums[w];
        if (tid < KC) binc[tid] = v + add;
        __syncthreads();
    }
    unsigned lo = (k > 0) ? binc[k - 1] : 0u;
    unsigned hi = binc[k];

    // my node's y0, unpacked once
    uint4 y0r = yT[n0 + tid];
    float y0f[8];
    {
        unsigned yw[4] = {y0r.x, y0r.y, y0r.z, y0r.w};
#pragma unroll
        for (int p = 0; p < 4; ++p) {
            y0f[2 * p]     = __uint_as_float(yw[p] << 16);
            y0f[2 * p + 1] = __uint_as_float(yw[p] & 0xFFFF0000u);
        }
    }
    float acc[8] = {0.f, 0.f, 0.f, 0.f, 0.f, 0.f, 0.f, 0.f};
    float dega = 0.f;

    for (unsigned cbase = lo; cbase < hi; cbase += SCAP) {
        unsigned cn = min((unsigned)SCAP, hi - cbase);
        bcnt[tid] = 0u;
        __syncthreads();
        // single coalesced global read of the chunk into registers
        uint2 rec[RPT];
#pragma unroll
        for (int j = 0; j < RPT; ++j) {
            unsigned o = (unsigned)tid + (unsigned)j * 512u;
            rec[j] = (o < cn) ? w0coef[cbase + o] : make_uint2(0u, 0u);
        }
        // pass1: count s0l from registers (cheap uint LDS atomics)
#pragma unroll
        for (int j = 0; j < RPT; ++j) {
            unsigned o = (unsigned)tid + (unsigned)j * 512u;
            if (o < cn) atomicAdd(&bcnt[rec[j].x >> 17], 1u);
        }
        __syncthreads();
        // exclusive scan of bcnt[512] across 8 waves
        unsigned myc = bcnt[tid];
        unsigned v = myc;
#pragma unroll
        for (int off = 1; off < 64; off <<= 1) {
            unsigned t = __shfl_up(v, off, 64);
            if (lane >= off) v += t;
        }
        if (lane == 63) wsums[wvi] = v;
        __syncthreads();
        unsigned add = 0;
#pragma unroll
        for (unsigned w = 0; w < 8; ++w)
            if (w < wvi) add += wsums[w];
        unsigned myoff = v + add - myc;
        bcur[tid] = myoff;
        __syncthreads();
        // pass2: scatter from registers into srt sorted by node
#pragma unroll
        for (int j = 0; j < RPT; ++j) {
            unsigned o = (unsigned)tid + (unsigned)j * 512u;
            if (o < cn) {
                unsigned slot = atomicAdd(&bcur[rec[j].x >> 17], 1u);
                srt[slot] = rec[j];
            }
        }
        __syncthreads();
        // owner phase: walk my run with a 2-deep prefetch pipeline
        unsigned s = myoff, e = myoff + myc;
        uint2 r0 = make_uint2(0u, 0u), r1 = make_uint2(0u, 0u);
        uint4 g0 = make_uint4(0u, 0u, 0u, 0u), g1 = g0;
        if (s < e)     { r0 = srt[s];     g0 = yT[r0.x & 0x1FFFFu]; }
        if (s + 1 < e) { r1 = srt[s + 1]; g1 = yT[r1.x & 0x1FFFFu]; }
        for (unsigned i = s; i < e; ++i) {
            uint2 rc = r0; uint4 gc = g0;
            r0 = r1; g0 = g1;
            if (i + 2 < e) { r1 = srt[i + 2]; g1 = yT[r1.x & 0x1FFFFu]; }
            float cf = __uint_as_float(rc.y & 0xFFFF0000u);
            float ge = __uint_as_float(rc.y << 16);
            unsigned gw[4] = {gc.x, gc.y, gc.z, gc.w};
#pragma unroll
            for (int p = 0; p < 4; ++p) {
                float ga = __uint_as_float(gw[p] << 16);
                float gb = __uint_as_float(gw[p] & 0xFFFF0000u);
                acc[2 * p]     += cf * fmaxf(y0f[2 * p]     - ga, 0.0f);
                acc[2 * p + 1] += cf * fmaxf(y0f[2 * p + 1] - gb, 0.0f);
            }
            dega += ge;
        }
        __syncthreads();   // all owners done before LDS reuse next chunk
    }

    // final write: out[b*N + n] = 1 - acc[b]/deg^2 (coalesced per batch)
    int n = n0 + tid;
    if (n < N) {
        float invd = (dega != 0.0f) ? 1.0f / (dega * dega) : 0.0f;
#pragma unroll
        for (int b = 0; b < BATCH; ++b)
            out[(size_t)b * N + n] = 1.0f - acc[b] * invd;
    }
}

// ---------------- fallback (R1 path) ----------------

__global__ void fill_one_kernel(float* __restrict__ out, int n) {
    int i = blockIdx.x * blockDim.x + threadIdx.x;
    if (i < n) out[i] = 1.0f;
}

__global__ void zero_kernel(float* __restrict__ p, int n) {
    int i = blockIdx.x * blockDim.x + threadIdx.x;
    if (i < n) p[i] = 0.0f;
}

__global__ void deg_kernel(const float* __restrict__ gea,
                           const int* __restrict__ ei0,
                           float* __restrict__ deg, int E) {
    int e = blockIdx.x * blockDim.x + threadIdx.x;
    if (e < E) atomicAdd(&deg[ei0[e]], gea[e]);
}

__global__ void edge_kernel(const float* __restrict__ y,
                            const float* __restrict__ dw,
                            const int* __restrict__ ei0,
                            const int* __restrict__ ei1,
                            const float* __restrict__ deg,
                            float* __restrict__ out,
                            int E, int N) {
    int e = blockIdx.x * blockDim.x + threadIdx.x;
    if (e >= E) return;
    int s0 = ei0[e];
    int s1 = ei1[e];
    float d = deg[s0];
    float inv = 1.0f / (d * d);
    float sig = 1.0f / (1.0f + __expf(-dw[e]));
    float coef = sqrtf(sig) * inv;
#pragma unroll
    for (int b = 0; b < BATCH; ++b) {
        float y0 = y[(size_t)b * N + s0];
        float y1 = y[(size_t)b * N + s1];
        float gm = coef * fmaxf(y0 - y1, 0.0f);
        if (gm != 0.0f) atomicAdd(&out[(size_t)b * N + s0], -gm);
    }
}

// ---------------- launch ----------------

extern "C" void kernel_launch(void* const* d_in, const int* in_sizes, int n_in,
                              void* d_out, int out_size, void* d_ws, size_t ws_size,
                              hipStream_t stream) {
    const float* y   = (const float*)d_in[0];   // [B,N]
    const float* gea = (const float*)d_in[2];   // [E]
    const float* dw  = (const float*)d_in[3];   // [E]
    const int*   ei  = (const int*)d_in[4];     // [2,E]

    const int E = in_sizes[2];
    const int N = in_sizes[0] / BATCH;
    const int* ei0 = ei;
    const int* ei1 = ei + E;

    const int K = (N + SBUCKET - 1) >> S_LOG;
    const int Npad = K << S_LOG;

    size_t o_yT     = 0;
    size_t o_rcf    = o_yT     + alignup((size_t)Npad * 16);
    size_t o_counts = o_rcf    + alignup((size_t)E * 8);
    size_t o_base   = o_counts + alignup((size_t)KC * CB * 4);
    size_t o_tot    = o_base   + alignup((size_t)KC * CB * 4);
    size_t need     = o_tot    + alignup((size_t)KC * 4);

    if (K <= KC && N <= 131071 && ws_size >= need) {
        char* w = (char*)d_ws;
        uint4*    yT     = (uint4*)(w + o_yT);
        uint2*    w0coef = (uint2*)(w + o_rcf);
        unsigned* counts = (unsigned*)(w + o_counts);
        unsigned* base   = (unsigned*)(w + o_base);
        unsigned* tot    = (unsigned*)(w + o_tot);

        int tb = (Npad + 255) / 256;
        count_transpose_kernel<<<CB + tb, 256, 0, stream>>>(ei0, counts, y, yT,
                                                            E, N, Npad);
        scanB1_kernel<<<K, 256, 0, stream>>>(counts, base, tot);
        scatter_kernel<<<CB, 512, 0, stream>>>(ei0, ei1, dw, gea, base, tot,
                                               w0coef, E, K);
        accum_kernel<<<K, 512, 0, stream>>>(w0coef, tot, yT, (float*)d_out, N, K);
    } else {
        float* deg = (float*)d_ws;
        zero_kernel<<<(N + 255) / 256, 256, 0, stream>>>(deg, N);
        fill_one_kernel<<<(out_size + 255) / 256, 256, 0, stream>>>((float*)d_out, out_size);
        deg_kernel<<<(E + 255) / 256, 256, 0, stream>>>(gea, ei0, deg, E);
        edge_kernel<<<(E + 255) / 256, 256, 0, stream>>>(y, dw, ei0, ei1, deg,
                                                         (float*)d_out, E, N);
    }
}